// Round 5
// baseline (283.011 us; speedup 1.0000x reference)
//
#include <hip/hip_runtime.h>
#include <cstddef>
#include <cstdint>

// SpatialPatchMoE on MI355X (gfx950).
// x[2,64,8,128,128] f32 -> 512 patches x 8 l-slices; router top-2/8;
// per expert: dwconv(1,7,7) -> LN(8,8) -> pw 64->128 -> silu*gate -> pw 64->64;
// out = x + sum_k w_k * expert_k.  Pointwise matmuls = bf16 MFMA 16x16x32.
//
// ws layout (bytes):
//   partial_l : f32 [n][l][c]      @ 0         (1048576)
//   dwT       : f32 [e][tap][c]    @ 1048576   (100352)
//   sel_i     : int[2*512]         @ 1148928   (4096)
//   sel_w     : f32[2*512]         @ 1153024   (4096)
//   wInBf     : bf16 [e][128][64]  @ 1157120   (131072)
//   wOutBf    : bf16 [e][64][64]   @ 1288192   (65536)
//   xr        : f32 [n*8+l][c][px] @ 1353728   (67108864)   (repack path)

typedef __attribute__((ext_vector_type(8))) short short8;
typedef __attribute__((ext_vector_type(4))) float f32x4;

#define REPACK_NEED 68462592ull

__device__ __forceinline__ unsigned short f2bf(float f) {
  unsigned u = __builtin_bit_cast(unsigned, f);
  unsigned r = (u + 0x7FFFu + ((u >> 16) & 1u)) >> 16;
  return (unsigned short)r;
}

__device__ __forceinline__ float wave_sum64(float v) {
#pragma unroll
  for (int m = 32; m > 0; m >>= 1) v += __shfl_xor(v, m, 64);
  return v;
}

// ---------------- preprocess: dw transpose + pw weights -> bf16
__global__ void k_pre(const float* __restrict__ dw,
                      const float* __restrict__ pwin,
                      const float* __restrict__ pwout,
                      float* __restrict__ dwT,
                      unsigned short* __restrict__ wIn,
                      unsigned short* __restrict__ wOut) {
  int idx = blockIdx.x * 256 + threadIdx.x;
  if (idx < 25088) {
    int e = idx / 3136;
    int r = idx - e * 3136;
    int c = r / 49;
    int tap = r - c * 49;
    dwT[(e * 49 + tap) * 64 + c] = dw[idx];
  } else if (idx < 25088 + 65536) {
    int i = idx - 25088;
    wIn[i] = f2bf(pwin[i]);
  } else if (idx < 25088 + 65536 + 32768) {
    int i = idx - 90624;
    wOut[i] = f2bf(pwout[i]);
  }
}

// ---------------- fallback patch sums (only when ws too small for repack)
__global__ __launch_bounds__(256) void k_sum(const float* __restrict__ x,
                                             float* __restrict__ partial_l) {
  __shared__ float red[256 * 17];
  int t = threadIdx.x, bid = blockIdx.x;
  int b = bid >> 8, c = (bid >> 2) & 63, lp = bid & 3;
  const float4* x4 = (const float4*)x + ((size_t)((b * 64 + c) * 8) + lp * 2) * 4096;
#pragma unroll 1
  for (int l2 = 0; l2 < 2; ++l2) {
    float acc[16];
#pragma unroll
    for (int k = 0; k < 16; ++k) acc[k] = 0.f;
#pragma unroll
    for (int k = 0; k < 16; ++k) {
      float4 v = x4[l2 * 4096 + k * 256 + t];
      acc[k] += v.x + v.y + v.z + v.w;
    }
    int pcol = (t & 31) >> 1;
    int slot = ((t & 1) << 3) | (t >> 5);
    __syncthreads();
#pragma unroll
    for (int k = 0; k < 16; ++k) red[(k * 16 + pcol) * 17 + slot] = acc[k];
    __syncthreads();
    float s = 0.f;
#pragma unroll
    for (int j = 0; j < 16; ++j) s += red[t * 17 + j];
    partial_l[((size_t)(b * 256 + t)) * 512 + (lp * 2 + l2) * 64 + c] = s;
  }
}

// ---------------- repack x -> patch-major xr[(n*8+l)][c][px], fused patch sums
__global__ __launch_bounds__(256) void k_repack(const float* __restrict__ x,
                                                float* __restrict__ xr,
                                                float* __restrict__ partial_l) {
  __shared__ __align__(16) float lt[8 * 1060];
  int t = threadIdx.x, bid = blockIdx.x;
  int ct = bid & 7, hh = (bid >> 3) & 15, l = (bid >> 7) & 7, b = bid >> 10;
  int c0 = ct * 8;
  const float4* x4 = (const float4*)x;
  float4* xr4 = (float4*)xr;
  int y = t >> 5, xq = t & 31;
#pragma unroll
  for (int i = 0; i < 8; ++i) {
    size_t src = ((size_t)((b * 64 + c0 + i) * 8 + l) << 12) +
                 (size_t)(hh * 8 + y) * 32 + xq;
    float4 v = x4[src];
    *(float4*)(lt + i * 1060 + y * 132 + xq * 4) = v;
  }
  __syncthreads();
  int cc = (t >> 4) & 7, ihalf = t >> 7, pxq = t & 15;
  int py = pxq >> 1, xcol = pxq & 1;
#pragma unroll
  for (int iw = 0; iw < 8; ++iw) {
    int ww = ihalf * 8 + iw;
    float4 v = *(const float4*)(lt + cc * 1060 + py * 132 + ww * 8 + xcol * 4);
    int n = b * 256 + hh * 16 + ww;
    xr4[((size_t)(n * 8 + l) << 10) + (c0 + cc) * 16 + pxq] = v;
    float s = v.x + v.y + v.z + v.w;
#pragma unroll
    for (int m = 1; m < 16; m <<= 1) s += __shfl_xor(s, m, 64);
    if (pxq == 0) partial_l[(size_t)(n * 8 + l) * 64 + c0 + cc] = s;
  }
}

// ---------------- router
__global__ void k_router(const float* __restrict__ partial_l,
                         const float* __restrict__ rw, const float* __restrict__ rb,
                         int* __restrict__ sel_i, float* __restrict__ sel_w) {
  int n = blockIdx.x;
  int lane = threadIdx.x;
  float s = 0.f;
#pragma unroll
  for (int l = 0; l < 8; ++l)
    s += partial_l[(size_t)n * 512 + l * 64 + lane];
  float rin = s * (1.f / 512.f);
  float lg[8];
#pragma unroll
  for (int e = 0; e < 8; ++e) {
    float v = rin * rw[e * 64 + lane];
    lg[e] = wave_sum64(v) + rb[e];
  }
  int e0 = 0; float v0 = lg[0];
#pragma unroll
  for (int e = 1; e < 8; ++e) if (lg[e] > v0) { v0 = lg[e]; e0 = e; }
  int e1 = -1; float v1 = -1e30f;
#pragma unroll
  for (int e = 0; e < 8; ++e) if (e != e0 && lg[e] > v1) { v1 = lg[e]; e1 = e; }
  if (lane == 0) {
    float w1 = __expf(v1 - v0);
    float z = 1.f + w1;
    sel_i[2 * n] = e0; sel_i[2 * n + 1] = e1;
    sel_w[2 * n] = 1.f / z; sel_w[2 * n + 1] = w1 / z;
  }
}

// ---------------- depthwise conv: weights read from LDS inline (short live
// ranges -> no spill, no remat); wave owns output rows Y0, Y0+1
template <int Y0>
__device__ __forceinline__ void convRows(const float* __restrict__ rowp,
                                         const float* __restrict__ wl,
                                         float* __restrict__ hv) {
  constexpr int RLO = (Y0 - 3 < 0) ? 0 : Y0 - 3;
  constexpr int RHI = (Y0 + 4 > 7) ? 7 : Y0 + 4;
#pragma unroll
  for (int r = RLO; r <= RHI; ++r) {
    float2 p0 = *(const float2*)(rowp + r * 8);
    float2 p1 = *(const float2*)(rowp + r * 8 + 2);
    float2 p2 = *(const float2*)(rowp + r * 8 + 4);
    float2 p3 = *(const float2*)(rowp + r * 8 + 6);
    const float row[8] = {p0.x, p0.y, p1.x, p1.y, p2.x, p2.y, p3.x, p3.y};
#pragma unroll
    for (int ry = 0; ry < 2; ++ry) {
      const int dy = r - (Y0 + ry) + 3;
      if (dy >= 0 && dy <= 6) {
#pragma unroll
        for (int dx = 0; dx < 7; ++dx) {
          float wt = wl[(dy * 7 + dx) * 64];   // ds_read_b32, conflict-free
#pragma unroll
          for (int xp = 0; xp < 8; ++xp) {
            const int xx = xp + dx - 3;
            if (xx >= 0 && xx < 8)
              hv[ry * 8 + xp] += row[xx] * wt;
          }
        }
      }
    }
  }
}

// ---------------- main: one block per (patch n, depth l); 4 waves
template <bool REPACK>
__global__ __launch_bounds__(256, 4) void k_main(
    const float* __restrict__ x, const float* __restrict__ xr,
    const float* __restrict__ dwT, const float* __restrict__ dwb,
    const float* __restrict__ lnw, const float* __restrict__ lnb,
    const float* __restrict__ pwin_b, const float* __restrict__ pwout_b,
    const unsigned short* __restrict__ wInBf,
    const unsigned short* __restrict__ wOutBf,
    const int* __restrict__ sel_i, const float* __restrict__ sel_w,
    float* __restrict__ out) {
  // carve: wsdw f32[3136] @0 | hbf u16[64*72] @12544 | lnred f32[512] @21760
  //        | xs f32[64*66] @23808  => 40704 B total (4 blocks/CU)
  __shared__ __align__(16) char smem[40704];
  float* wsdw         = (float*)smem;
  unsigned short* hbf = (unsigned short*)(smem + 12544);
  float* lnred        = (float*)(smem + 21760);
  float* xs           = (float*)(smem + 23808);
  float* eb           = (float*)smem;   // epilogue alias over wsdw+hbf

  const int t = threadIdx.x;
  const int lane = t & 63;
  const int wv = __builtin_amdgcn_readfirstlane(t >> 6);
  const int r15 = lane & 15, r4 = lane >> 4;
  const int bidx = blockIdx.x;
  const int n = bidx >> 3, l = bidx & 7;
  const int b = n >> 8, p = n & 255;
  const int hh = p >> 4, ww = p & 15;
  const size_t obase = (size_t)b * 8388608 + (size_t)l * 16384 +
                       (size_t)hh * 1024 + (size_t)ww * 8;

  // ---- stage x slice -> xs [c][px] stride 66 (float2 granularity)
#pragma unroll
  for (int i = 0; i < 4; ++i) {
    int g = i * 256 + t;
    int c = g >> 4, q = g & 15;
    float4 v;
    if constexpr (REPACK)
      v = ((const float4*)xr)[(size_t)bidx * 1024 + g];
    else
      v = *(const float4*)(x + obase + (size_t)c * 131072 + (q >> 1) * 128 + (q & 1) * 4);
    *(float2*)(xs + c * 66 + q * 4)     = float2{v.x, v.y};
    *(float2*)(xs + c * 66 + q * 4 + 2) = float2{v.z, v.w};
  }

  float oacc[16];
#pragma unroll
  for (int i = 0; i < 16; ++i) oacc[i] = 0.f;

#pragma unroll 1
  for (int k = 0; k < 2; ++k) {
    const int e = __builtin_amdgcn_readfirstlane(sel_i[2 * n + k]);
    const float we = sel_w[2 * n + k];

    // ---- stage expert dw weights into LDS (784 float4)
    {
      const float4* src = (const float4*)(dwT + e * 3136);
      float4* dst = (float4*)wsdw;
#pragma unroll
      for (int i = 0; i < 3; ++i) dst[i * 256 + t] = src[i * 256 + t];
      if (t < 16) dst[768 + t] = src[768 + t];
    }
    __syncthreads();  // syncW: wsdw + xs ready (k=0); guards hbf reuse (k=1)

    // ---- depthwise conv: lane = channel; weights read inline from LDS
    float hv[16];
    {
      const float bias = dwb[e * 64 + lane];
#pragma unroll
      for (int j = 0; j < 16; ++j) hv[j] = bias;
    }
    const float* rowp = xs + lane * 66;
    const float* wl = wsdw + lane;
    if (wv == 0)      convRows<0>(rowp, wl, hv);
    else if (wv == 1) convRows<2>(rowp, wl, hv);
    else if (wv == 2) convRows<4>(rowp, wl, hv);
    else              convRows<6>(rowp, wl, hv);

    // ---- LayerNorm over 64 pixels per channel
    float ps = 0.f, pq = 0.f;
#pragma unroll
    for (int j = 0; j < 16; ++j) { ps += hv[j]; pq += hv[j] * hv[j]; }
    lnred[(wv * 2 + 0) * 64 + lane] = ps;
    lnred[(wv * 2 + 1) * 64 + lane] = pq;
    __syncthreads();  // sync1
    float sm = lnred[0 * 64 + lane] + lnred[2 * 64 + lane] +
               lnred[4 * 64 + lane] + lnred[6 * 64 + lane];
    float sq = lnred[1 * 64 + lane] + lnred[3 * 64 + lane] +
               lnred[5 * 64 + lane] + lnred[7 * 64 + lane];
    float mu = sm * (1.f / 64.f);
    float var = sq * (1.f / 64.f) - mu * mu;
    float rstd = rsqrtf(var + 1e-5f);
#pragma unroll
    for (int j = 0; j < 16; ++j) {
      int s = 16 * wv + j;  // pixel index owned by this wave
      float nv = (hv[j] - mu) * rstd * lnw[e * 64 + s] + lnb[e * 64 + s];
      hbf[s * 72 + lane] = f2bf(nv);  // h[px][c] bf16, stride 72
    }
    __syncthreads();  // sync2: h ready

    // ---- pw_in (64->128) MFMA; wave owns A-rows [16wv,+16) and gate rows +64
    const unsigned short* wInE = wInBf + (size_t)e * 8192;
    short8 aA[2], aG[2];
#pragma unroll
    for (int kf = 0; kf < 2; ++kf) {
      aA[kf] = *(const short8*)(wInE + (16 * wv + r15) * 64 + kf * 32 + r4 * 8);
      aG[kf] = *(const short8*)(wInE + (64 + 16 * wv + r15) * 64 + kf * 32 + r4 * 8);
    }
    f32x4 accA[4], accG[4];
#pragma unroll
    for (int nt = 0; nt < 4; ++nt)
#pragma unroll
      for (int v = 0; v < 4; ++v) {
        accA[nt][v] = pwin_b[e * 128 + 16 * wv + r4 * 4 + v];
        accG[nt][v] = pwin_b[e * 128 + 64 + 16 * wv + r4 * 4 + v];
      }
#pragma unroll
    for (int nt = 0; nt < 4; ++nt)
#pragma unroll
      for (int kf = 0; kf < 2; ++kf) {
        short8 bfr = *(const short8*)(hbf + (16 * nt + r15) * 72 + kf * 32 + r4 * 8);
        accA[nt] = __builtin_amdgcn_mfma_f32_16x16x32_bf16(aA[kf], bfr, accA[nt], 0, 0, 0);
        accG[nt] = __builtin_amdgcn_mfma_f32_16x16x32_bf16(aG[kf], bfr, accG[nt], 0, 0, 0);
      }
    // silu(a)*g in regs, pack to 2x u32 per nt
    unsigned h3p[4][2];
#pragma unroll
    for (int nt = 0; nt < 4; ++nt) {
      float hval[4];
#pragma unroll
      for (int v = 0; v < 4; ++v) {
        float a = accA[nt][v];
        float g = accG[nt][v];
        hval[v] = (a / (1.f + __expf(-a))) * g;
      }
      h3p[nt][0] = (unsigned)f2bf(hval[0]) | ((unsigned)f2bf(hval[1]) << 16);
      h3p[nt][1] = (unsigned)f2bf(hval[2]) | ((unsigned)f2bf(hval[3]) << 16);
    }
    __syncthreads();  // sync2b: all hbf(h) reads done
#pragma unroll
    for (int nt = 0; nt < 4; ++nt) {
      uint2 w2; w2.x = h3p[nt][0]; w2.y = h3p[nt][1];
      *(uint2*)(hbf + (16 * nt + r15) * 72 + 16 * wv + 4 * r4) = w2;  // h3 over h
    }
    __syncthreads();  // sync3: h3 ready

    // ---- pw_out (64->64) MFMA
    const unsigned short* wOutE = wOutBf + (size_t)e * 4096;
    short8 aO[2];
#pragma unroll
    for (int kf = 0; kf < 2; ++kf)
      aO[kf] = *(const short8*)(wOutE + (16 * wv + r15) * 64 + kf * 32 + r4 * 8);
    f32x4 accO[4];
#pragma unroll
    for (int nt = 0; nt < 4; ++nt)
#pragma unroll
      for (int v = 0; v < 4; ++v) accO[nt][v] = 0.f;
#pragma unroll
    for (int nt = 0; nt < 4; ++nt)
#pragma unroll
      for (int kf = 0; kf < 2; ++kf) {
        short8 bfr = *(const short8*)(hbf + (16 * nt + r15) * 72 + kf * 32 + r4 * 8);
        accO[nt] = __builtin_amdgcn_mfma_f32_16x16x32_bf16(aO[kf], bfr, accO[nt], 0, 0, 0);
      }
    float bO[4];
#pragma unroll
    for (int v = 0; v < 4; ++v) bO[v] = pwout_b[e * 64 + 16 * wv + r4 * 4 + v];
#pragma unroll
    for (int nt = 0; nt < 4; ++nt)
#pragma unroll
      for (int v = 0; v < 4; ++v) oacc[nt * 4 + v] += we * (accO[nt][v] + bO[v]);
  }

  // ---- epilogue: oacc -> eb (stride 68, aliases wsdw+hbf), residual + store
  __syncthreads();  // all hbf(h3) reads done before alias write
#pragma unroll
  for (int nt = 0; nt < 4; ++nt)
#pragma unroll
    for (int v = 0; v < 4; ++v)
      eb[(16 * wv + 4 * r4 + v) * 68 + 16 * nt + r15] = oacc[nt * 4 + v];
  __syncthreads();
#pragma unroll
  for (int i = 0; i < 4; ++i) {
    int g = i * 256 + t;
    int c = g >> 4, q = g & 15;
    float4 dv = *(const float4*)(eb + c * 68 + q * 4);
    float2 x01 = *(const float2*)(xs + c * 66 + q * 4);
    float2 x23 = *(const float2*)(xs + c * 66 + q * 4 + 2);
    float4 o4 = {x01.x + dv.x, x01.y + dv.y, x23.x + dv.z, x23.y + dv.w};
    *(float4*)(out + obase + (size_t)c * 131072 + (q >> 1) * 128 + (q & 1) * 4) = o4;
  }
}

extern "C" void kernel_launch(void* const* d_in, const int* in_sizes, int n_in,
                              void* d_out, int out_size, void* d_ws, size_t ws_size,
                              hipStream_t stream) {
  const float* x       = (const float*)d_in[0];
  const float* rw      = (const float*)d_in[1];
  const float* rb      = (const float*)d_in[2];
  const float* dww     = (const float*)d_in[3];
  const float* dwb     = (const float*)d_in[4];
  const float* lnw     = (const float*)d_in[5];
  const float* lnb     = (const float*)d_in[6];
  const float* pwin_w  = (const float*)d_in[7];
  const float* pwin_b  = (const float*)d_in[8];
  const float* pwout_w = (const float*)d_in[9];
  const float* pwout_b = (const float*)d_in[10];
  float* out = (float*)d_out;

  char* ws = (char*)d_ws;
  float*          partial_l = (float*)ws;
  float*          dwT       = (float*)(ws + 1048576);
  int*            sel_i     = (int*)(ws + 1148928);
  float*          sel_w     = (float*)(ws + 1153024);
  unsigned short* wInBf     = (unsigned short*)(ws + 1157120);
  unsigned short* wOutBf    = (unsigned short*)(ws + 1288192);
  float*          xr        = (float*)(ws + 1353728);

  const bool repack = ws_size >= REPACK_NEED;

  hipLaunchKernelGGL(k_pre, dim3(482), dim3(256), 0, stream,
                     dww, pwin_w, pwout_w, dwT, wInBf, wOutBf);
  if (repack)
    hipLaunchKernelGGL(k_repack, dim3(2048), dim3(256), 0, stream, x, xr, partial_l);
  else
    hipLaunchKernelGGL(k_sum, dim3(512), dim3(256), 0, stream, x, partial_l);
  hipLaunchKernelGGL(k_router, dim3(512), dim3(64), 0, stream,
                     partial_l, rw, rb, sel_i, sel_w);
  if (repack)
    hipLaunchKernelGGL((k_main<true>), dim3(4096), dim3(256), 0, stream,
                       x, xr, dwT, dwb, lnw, lnb, pwin_b, pwout_b,
                       wInBf, wOutBf, sel_i, sel_w, out);
  else
    hipLaunchKernelGGL((k_main<false>), dim3(4096), dim3(256), 0, stream,
                       x, xr, dwT, dwb, lnw, lnb, pwin_b, pwout_b,
                       wInBf, wOutBf, sel_i, sel_w, out);
}

// Round 6
// 210.063 us; speedup vs baseline: 1.3473x; 1.3473x over previous
//
#include <hip/hip_runtime.h>
#include <cstddef>
#include <cstdint>

// SpatialPatchMoE on MI355X (gfx950).
// x[2,64,8,128,128] f32 -> 512 patches x 8 l-slices; router top-2/8;
// per expert: dwconv(1,7,7) -> LN(8,8) -> pw 64->128 -> silu*gate -> pw 64->64;
// out = x + sum_k w_k * expert_k.  Pointwise matmuls = bf16 MFMA 16x16x32.
//
// ws layout (bytes):
//   partial_l : f32 [n][l][c]      @ 0         (1048576)
//   dwT       : f32 [e][tap][c]    @ 1048576   (100352)
//   sel_i     : int[2*512]         @ 1148928   (4096)
//   sel_w     : f32[2*512]         @ 1153024   (4096)
//   wInBf     : bf16 [e][128][64]  @ 1157120   (131072)
//   wOutBf    : bf16 [e][64][64]   @ 1288192   (65536)
//   xr        : f32 [n*8+l][c][px] @ 1353728   (67108864)   (repack path)

typedef __attribute__((ext_vector_type(8))) short short8;
typedef __attribute__((ext_vector_type(4))) float f32x4;

#define REPACK_NEED 68462592ull

__device__ __forceinline__ unsigned short f2bf(float f) {
  unsigned u = __builtin_bit_cast(unsigned, f);
  unsigned r = (u + 0x7FFFu + ((u >> 16) & 1u)) >> 16;
  return (unsigned short)r;
}

__device__ __forceinline__ float wave_sum64(float v) {
#pragma unroll
  for (int m = 32; m > 0; m >>= 1) v += __shfl_xor(v, m, 64);
  return v;
}

// ---------------- preprocess: dw transpose + pw weights -> bf16
__global__ void k_pre(const float* __restrict__ dw,
                      const float* __restrict__ pwin,
                      const float* __restrict__ pwout,
                      float* __restrict__ dwT,
                      unsigned short* __restrict__ wIn,
                      unsigned short* __restrict__ wOut) {
  int idx = blockIdx.x * 256 + threadIdx.x;
  if (idx < 25088) {
    int e = idx / 3136;
    int r = idx - e * 3136;
    int c = r / 49;
    int tap = r - c * 49;
    dwT[(e * 49 + tap) * 64 + c] = dw[idx];
  } else if (idx < 25088 + 65536) {
    int i = idx - 25088;
    wIn[i] = f2bf(pwin[i]);
  } else if (idx < 25088 + 65536 + 32768) {
    int i = idx - 90624;
    wOut[i] = f2bf(pwout[i]);
  }
}

// ---------------- fallback patch sums (only when ws too small for repack)
__global__ __launch_bounds__(256) void k_sum(const float* __restrict__ x,
                                             float* __restrict__ partial_l) {
  __shared__ float red[256 * 17];
  int t = threadIdx.x, bid = blockIdx.x;
  int b = bid >> 8, c = (bid >> 2) & 63, lp = bid & 3;
  const float4* x4 = (const float4*)x + ((size_t)((b * 64 + c) * 8) + lp * 2) * 4096;
#pragma unroll 1
  for (int l2 = 0; l2 < 2; ++l2) {
    float acc[16];
#pragma unroll
    for (int k = 0; k < 16; ++k) acc[k] = 0.f;
#pragma unroll
    for (int k = 0; k < 16; ++k) {
      float4 v = x4[l2 * 4096 + k * 256 + t];
      acc[k] += v.x + v.y + v.z + v.w;
    }
    int pcol = (t & 31) >> 1;
    int slot = ((t & 1) << 3) | (t >> 5);
    __syncthreads();
#pragma unroll
    for (int k = 0; k < 16; ++k) red[(k * 16 + pcol) * 17 + slot] = acc[k];
    __syncthreads();
    float s = 0.f;
#pragma unroll
    for (int j = 0; j < 16; ++j) s += red[t * 17 + j];
    partial_l[((size_t)(b * 256 + t)) * 512 + (lp * 2 + l2) * 64 + c] = s;
  }
}

// ---------------- repack x -> patch-major xr[(n*8+l)][c][px], fused patch sums
__global__ __launch_bounds__(256) void k_repack(const float* __restrict__ x,
                                                float* __restrict__ xr,
                                                float* __restrict__ partial_l) {
  __shared__ __align__(16) float lt[8 * 1060];
  int t = threadIdx.x, bid = blockIdx.x;
  int ct = bid & 7, hh = (bid >> 3) & 15, l = (bid >> 7) & 7, b = bid >> 10;
  int c0 = ct * 8;
  const float4* x4 = (const float4*)x;
  float4* xr4 = (float4*)xr;
  int y = t >> 5, xq = t & 31;
#pragma unroll
  for (int i = 0; i < 8; ++i) {
    size_t src = ((size_t)((b * 64 + c0 + i) * 8 + l) << 12) +
                 (size_t)(hh * 8 + y) * 32 + xq;
    float4 v = x4[src];
    *(float4*)(lt + i * 1060 + y * 132 + xq * 4) = v;
  }
  __syncthreads();
  int cc = (t >> 4) & 7, ihalf = t >> 7, pxq = t & 15;
  int py = pxq >> 1, xcol = pxq & 1;
#pragma unroll
  for (int iw = 0; iw < 8; ++iw) {
    int ww = ihalf * 8 + iw;
    float4 v = *(const float4*)(lt + cc * 1060 + py * 132 + ww * 8 + xcol * 4);
    int n = b * 256 + hh * 16 + ww;
    xr4[((size_t)(n * 8 + l) << 10) + (c0 + cc) * 16 + pxq] = v;
    float s = v.x + v.y + v.z + v.w;
#pragma unroll
    for (int m = 1; m < 16; m <<= 1) s += __shfl_xor(s, m, 64);
    if (pxq == 0) partial_l[(size_t)(n * 8 + l) * 64 + c0 + cc] = s;
  }
}

// ---------------- router
__global__ void k_router(const float* __restrict__ partial_l,
                         const float* __restrict__ rw, const float* __restrict__ rb,
                         int* __restrict__ sel_i, float* __restrict__ sel_w) {
  int n = blockIdx.x;
  int lane = threadIdx.x;
  float s = 0.f;
#pragma unroll
  for (int l = 0; l < 8; ++l)
    s += partial_l[(size_t)n * 512 + l * 64 + lane];
  float rin = s * (1.f / 512.f);
  float lg[8];
#pragma unroll
  for (int e = 0; e < 8; ++e) {
    float v = rin * rw[e * 64 + lane];
    lg[e] = wave_sum64(v) + rb[e];
  }
  int e0 = 0; float v0 = lg[0];
#pragma unroll
  for (int e = 1; e < 8; ++e) if (lg[e] > v0) { v0 = lg[e]; e0 = e; }
  int e1 = -1; float v1 = -1e30f;
#pragma unroll
  for (int e = 0; e < 8; ++e) if (e != e0 && lg[e] > v1) { v1 = lg[e]; e1 = e; }
  if (lane == 0) {
    float w1 = __expf(v1 - v0);
    float z = 1.f + w1;
    sel_i[2 * n] = e0; sel_i[2 * n + 1] = e1;
    sel_w[2 * n] = 1.f / z; sel_w[2 * n + 1] = w1 / z;
  }
}

// ---------------- depthwise conv: weights read from LDS inline; wave owns
// output rows Y0, Y0+1
template <int Y0>
__device__ __forceinline__ void convRows(const float* __restrict__ rowp,
                                         const float* __restrict__ wl,
                                         float* __restrict__ hv) {
  constexpr int RLO = (Y0 - 3 < 0) ? 0 : Y0 - 3;
  constexpr int RHI = (Y0 + 4 > 7) ? 7 : Y0 + 4;
#pragma unroll
  for (int r = RLO; r <= RHI; ++r) {
    float2 p0 = *(const float2*)(rowp + r * 8);
    float2 p1 = *(const float2*)(rowp + r * 8 + 2);
    float2 p2 = *(const float2*)(rowp + r * 8 + 4);
    float2 p3 = *(const float2*)(rowp + r * 8 + 6);
    const float row[8] = {p0.x, p0.y, p1.x, p1.y, p2.x, p2.y, p3.x, p3.y};
#pragma unroll
    for (int ry = 0; ry < 2; ++ry) {
      const int dy = r - (Y0 + ry) + 3;
      if (dy >= 0 && dy <= 6) {
#pragma unroll
        for (int dx = 0; dx < 7; ++dx) {
          float wt = wl[(dy * 7 + dx) * 64];   // ds_read_b32, conflict-free
#pragma unroll
          for (int xp = 0; xp < 8; ++xp) {
            const int xx = xp + dx - 3;
            if (xx >= 0 && xx < 8)
              hv[ry * 8 + xp] += row[xx] * wt;
          }
        }
      }
    }
  }
}

// ---------------- main: one block per (patch n, depth l); 4 waves; 3 blocks/CU
template <bool REPACK>
__global__ __launch_bounds__(256, 3) void k_main(
    const float* __restrict__ x, const float* __restrict__ xr,
    const float* __restrict__ dwT, const float* __restrict__ dwb,
    const float* __restrict__ lnw, const float* __restrict__ lnb,
    const float* __restrict__ pwin_b, const float* __restrict__ pwout_b,
    const unsigned short* __restrict__ wInBf,
    const unsigned short* __restrict__ wOutBf,
    const int* __restrict__ sel_i, const float* __restrict__ sel_w,
    float* __restrict__ out) {
  // carve: wsdw f32[3136] @0 | hbf u16[64*72] @12544 | h3bf u16[64*72] @21760
  //        | lnred f32[512] @30976 | xs f32[64*66] @33024  => 49920 B (3/CU)
  __shared__ __align__(16) char smem[49920];
  float* wsdw          = (float*)smem;
  unsigned short* hbf  = (unsigned short*)(smem + 12544);
  unsigned short* h3bf = (unsigned short*)(smem + 21760);
  float* lnred         = (float*)(smem + 30976);
  float* xs            = (float*)(smem + 33024);
  float* eb            = (float*)smem;   // epilogue alias over wsdw+hbf (17408 B)

  const int t = threadIdx.x;
  const int lane = t & 63;
  const int wv = __builtin_amdgcn_readfirstlane(t >> 6);
  const int r15 = lane & 15, r4 = lane >> 4;
  const int bidx = blockIdx.x;
  const int n = bidx >> 3, l = bidx & 7;
  const int b = n >> 8, p = n & 255;
  const int hh = p >> 4, ww = p & 15;
  const size_t obase = (size_t)b * 8388608 + (size_t)l * 16384 +
                       (size_t)hh * 1024 + (size_t)ww * 8;

  // ---- stage x slice -> xs [c][px] stride 66 (float2 granularity)
#pragma unroll
  for (int i = 0; i < 4; ++i) {
    int g = i * 256 + t;
    int c = g >> 4, q = g & 15;
    float4 v;
    if constexpr (REPACK)
      v = ((const float4*)xr)[(size_t)bidx * 1024 + g];
    else
      v = *(const float4*)(x + obase + (size_t)c * 131072 + (q >> 1) * 128 + (q & 1) * 4);
    *(float2*)(xs + c * 66 + q * 4)     = float2{v.x, v.y};
    *(float2*)(xs + c * 66 + q * 4 + 2) = float2{v.z, v.w};
  }

  float oacc[16];
#pragma unroll
  for (int i = 0; i < 16; ++i) oacc[i] = 0.f;

#pragma unroll 1
  for (int k = 0; k < 2; ++k) {
    const int e = __builtin_amdgcn_readfirstlane(sel_i[2 * n + k]);
    const float we = sel_w[2 * n + k];

    // ---- stage expert dw weights into LDS (784 float4)
    {
      const float4* src = (const float4*)(dwT + e * 3136);
      float4* dst = (float4*)wsdw;
#pragma unroll
      for (int i = 0; i < 3; ++i) dst[i * 256 + t] = src[i * 256 + t];
      if (t < 16) dst[768 + t] = src[768 + t];
    }
    __syncthreads();  // syncW: wsdw + xs ready (k=0); guards hbf/h3bf reuse (k=1)

    // ---- depthwise conv: lane = channel; weights read inline from LDS
    float hv[16];
    {
      const float bias = dwb[e * 64 + lane];
#pragma unroll
      for (int j = 0; j < 16; ++j) hv[j] = bias;
    }
    const float* rowp = xs + lane * 66;
    const float* wl = wsdw + lane;
    if (wv == 0)      convRows<0>(rowp, wl, hv);
    else if (wv == 1) convRows<2>(rowp, wl, hv);
    else if (wv == 2) convRows<4>(rowp, wl, hv);
    else              convRows<6>(rowp, wl, hv);

    // ---- LayerNorm over 64 pixels per channel
    float ps = 0.f, pq = 0.f;
#pragma unroll
    for (int j = 0; j < 16; ++j) { ps += hv[j]; pq += hv[j] * hv[j]; }
    lnred[(wv * 2 + 0) * 64 + lane] = ps;
    lnred[(wv * 2 + 1) * 64 + lane] = pq;
    __syncthreads();  // sync1
    float sm = lnred[0 * 64 + lane] + lnred[2 * 64 + lane] +
               lnred[4 * 64 + lane] + lnred[6 * 64 + lane];
    float sq = lnred[1 * 64 + lane] + lnred[3 * 64 + lane] +
               lnred[5 * 64 + lane] + lnred[7 * 64 + lane];
    float mu = sm * (1.f / 64.f);
    float var = sq * (1.f / 64.f) - mu * mu;
    float rstd = rsqrtf(var + 1e-5f);
#pragma unroll
    for (int j = 0; j < 16; ++j) {
      int s = 16 * wv + j;  // pixel index owned by this wave
      float nv = (hv[j] - mu) * rstd * lnw[e * 64 + s] + lnb[e * 64 + s];
      hbf[s * 72 + lane] = f2bf(nv);  // h[px][c] bf16, stride 72
    }
    __syncthreads();  // sync2: h ready

    // ---- pw_in (64->128) MFMA; wave owns A-rows [16wv,+16) and gate rows +64
    const unsigned short* wInE = wInBf + (size_t)e * 8192;
    short8 aA[2], aG[2];
#pragma unroll
    for (int kf = 0; kf < 2; ++kf) {
      aA[kf] = *(const short8*)(wInE + (16 * wv + r15) * 64 + kf * 32 + r4 * 8);
      aG[kf] = *(const short8*)(wInE + (64 + 16 * wv + r15) * 64 + kf * 32 + r4 * 8);
    }
    f32x4 accA[4], accG[4];
#pragma unroll
    for (int nt = 0; nt < 4; ++nt)
#pragma unroll
      for (int v = 0; v < 4; ++v) {
        accA[nt][v] = pwin_b[e * 128 + 16 * wv + r4 * 4 + v];
        accG[nt][v] = pwin_b[e * 128 + 64 + 16 * wv + r4 * 4 + v];
      }
#pragma unroll
    for (int nt = 0; nt < 4; ++nt)
#pragma unroll
      for (int kf = 0; kf < 2; ++kf) {
        short8 bfr = *(const short8*)(hbf + (16 * nt + r15) * 72 + kf * 32 + r4 * 8);
        accA[nt] = __builtin_amdgcn_mfma_f32_16x16x32_bf16(aA[kf], bfr, accA[nt], 0, 0, 0);
        accG[nt] = __builtin_amdgcn_mfma_f32_16x16x32_bf16(aG[kf], bfr, accG[nt], 0, 0, 0);
      }
    // silu(a)*g -> h3 (separate buffer; no extra barrier needed)
#pragma unroll
    for (int nt = 0; nt < 4; ++nt) {
      float hval[4];
#pragma unroll
      for (int v = 0; v < 4; ++v) {
        float a = accA[nt][v];
        float g = accG[nt][v];
        hval[v] = (a / (1.f + __expf(-a))) * g;
      }
      uint2 w2;
      w2.x = (unsigned)f2bf(hval[0]) | ((unsigned)f2bf(hval[1]) << 16);
      w2.y = (unsigned)f2bf(hval[2]) | ((unsigned)f2bf(hval[3]) << 16);
      *(uint2*)(h3bf + (16 * nt + r15) * 72 + 16 * wv + 4 * r4) = w2;
    }
    __syncthreads();  // sync3: h3 ready

    // ---- pw_out (64->64) MFMA
    const unsigned short* wOutE = wOutBf + (size_t)e * 4096;
    short8 aO[2];
#pragma unroll
    for (int kf = 0; kf < 2; ++kf)
      aO[kf] = *(const short8*)(wOutE + (16 * wv + r15) * 64 + kf * 32 + r4 * 8);
    f32x4 accO[4];
#pragma unroll
    for (int nt = 0; nt < 4; ++nt)
#pragma unroll
      for (int v = 0; v < 4; ++v) accO[nt][v] = 0.f;
#pragma unroll
    for (int nt = 0; nt < 4; ++nt)
#pragma unroll
      for (int kf = 0; kf < 2; ++kf) {
        short8 bfr = *(const short8*)(h3bf + (16 * nt + r15) * 72 + kf * 32 + r4 * 8);
        accO[nt] = __builtin_amdgcn_mfma_f32_16x16x32_bf16(aO[kf], bfr, accO[nt], 0, 0, 0);
      }
    float bO[4];
#pragma unroll
    for (int v = 0; v < 4; ++v) bO[v] = pwout_b[e * 64 + 16 * wv + r4 * 4 + v];
#pragma unroll
    for (int nt = 0; nt < 4; ++nt)
#pragma unroll
      for (int v = 0; v < 4; ++v) oacc[nt * 4 + v] += we * (accO[nt][v] + bO[v]);
  }

  // ---- epilogue: oacc -> eb (stride 68, aliases wsdw+hbf — both regions are
  //      only read before sync3, so no barrier needed before the write)
#pragma unroll
  for (int nt = 0; nt < 4; ++nt)
#pragma unroll
    for (int v = 0; v < 4; ++v)
      eb[(16 * wv + 4 * r4 + v) * 68 + 16 * nt + r15] = oacc[nt * 4 + v];
  __syncthreads();
#pragma unroll
  for (int i = 0; i < 4; ++i) {
    int g = i * 256 + t;
    int c = g >> 4, q = g & 15;
    float4 dv = *(const float4*)(eb + c * 68 + q * 4);
    float2 x01 = *(const float2*)(xs + c * 66 + q * 4);
    float2 x23 = *(const float2*)(xs + c * 66 + q * 4 + 2);
    float4 o4 = {x01.x + dv.x, x01.y + dv.y, x23.x + dv.z, x23.y + dv.w};
    *(float4*)(out + obase + (size_t)c * 131072 + (q >> 1) * 128 + (q & 1) * 4) = o4;
  }
}

extern "C" void kernel_launch(void* const* d_in, const int* in_sizes, int n_in,
                              void* d_out, int out_size, void* d_ws, size_t ws_size,
                              hipStream_t stream) {
  const float* x       = (const float*)d_in[0];
  const float* rw      = (const float*)d_in[1];
  const float* rb      = (const float*)d_in[2];
  const float* dww     = (const float*)d_in[3];
  const float* dwb     = (const float*)d_in[4];
  const float* lnw     = (const float*)d_in[5];
  const float* lnb     = (const float*)d_in[6];
  const float* pwin_w  = (const float*)d_in[7];
  const float* pwin_b  = (const float*)d_in[8];
  const float* pwout_w = (const float*)d_in[9];
  const float* pwout_b = (const float*)d_in[10];
  float* out = (float*)d_out;

  char* ws = (char*)d_ws;
  float*          partial_l = (float*)ws;
  float*          dwT       = (float*)(ws + 1048576);
  int*            sel_i     = (int*)(ws + 1148928);
  float*          sel_w     = (float*)(ws + 1153024);
  unsigned short* wInBf     = (unsigned short*)(ws + 1157120);
  unsigned short* wOutBf    = (unsigned short*)(ws + 1288192);
  float*          xr        = (float*)(ws + 1353728);

  const bool repack = ws_size >= REPACK_NEED;

  hipLaunchKernelGGL(k_pre, dim3(482), dim3(256), 0, stream,
                     dww, pwin_w, pwout_w, dwT, wInBf, wOutBf);
  if (repack)
    hipLaunchKernelGGL(k_repack, dim3(2048), dim3(256), 0, stream, x, xr, partial_l);
  else
    hipLaunchKernelGGL(k_sum, dim3(512), dim3(256), 0, stream, x, partial_l);
  hipLaunchKernelGGL(k_router, dim3(512), dim3(64), 0, stream,
                     partial_l, rw, rb, sel_i, sel_w);
  if (repack)
    hipLaunchKernelGGL((k_main<true>), dim3(4096), dim3(256), 0, stream,
                       x, xr, dwT, dwb, lnw, lnb, pwin_b, pwout_b,
                       wInBf, wOutBf, sel_i, sel_w, out);
  else
    hipLaunchKernelGGL((k_main<false>), dim3(4096), dim3(256), 0, stream,
                       x, xr, dwT, dwb, lnw, lnb, pwin_b, pwout_b,
                       wInBf, wOutBf, sel_i, sel_w, out);
}

// Round 7
// 146.594 us; speedup vs baseline: 1.9306x; 1.4330x over previous
//
#include <hip/hip_runtime.h>
#include <cstddef>
#include <cstdint>

// SpatialPatchMoE on MI355X (gfx950).
// x[2,64,8,128,128] f32 -> 512 patches x 8 l-slices; router top-2/8;
// per expert: dwconv(1,7,7) -> LN(8,8) -> pw 64->128 -> silu*gate -> pw 64->64;
// out = x + sum_k w_k * expert_k.  Pointwise matmuls = bf16 MFMA 16x16x32.
//
// k_main: 512 threads = 8 waves; wave wv owns conv row wv (8 px) and MFMA
// row-tile (wv>>1) x px-half (wv&1).  No __launch_bounds__ min-waves: rounds
// 4-6 proved the min-waves cap makes the allocator spill (~300-500 MB scratch
// traffic); instead per-thread state is halved structurally.
//
// ws layout (bytes):
//   partial_l : f32 [n][l][c]      @ 0         (1048576)
//   dwT       : f32 [e][tap][c]    @ 1048576   (100352)
//   sel_i     : int[2*512]         @ 1148928   (4096)
//   sel_w     : f32[2*512]         @ 1153024   (4096)
//   wInBf     : bf16 [e][128][64]  @ 1157120   (131072)
//   wOutBf    : bf16 [e][64][64]   @ 1288192   (65536)
//   xr        : f32 [n*8+l][c][px] @ 1353728   (67108864)   (repack path)

typedef __attribute__((ext_vector_type(8))) short short8;
typedef __attribute__((ext_vector_type(4))) float f32x4;

#define REPACK_NEED 68462592ull

__device__ __forceinline__ unsigned short f2bf(float f) {
  unsigned u = __builtin_bit_cast(unsigned, f);
  unsigned r = (u + 0x7FFFu + ((u >> 16) & 1u)) >> 16;
  return (unsigned short)r;
}

__device__ __forceinline__ float wave_sum64(float v) {
#pragma unroll
  for (int m = 32; m > 0; m >>= 1) v += __shfl_xor(v, m, 64);
  return v;
}

// ---------------- preprocess: dw transpose + pw weights -> bf16
__global__ void k_pre(const float* __restrict__ dw,
                      const float* __restrict__ pwin,
                      const float* __restrict__ pwout,
                      float* __restrict__ dwT,
                      unsigned short* __restrict__ wIn,
                      unsigned short* __restrict__ wOut) {
  int idx = blockIdx.x * 256 + threadIdx.x;
  if (idx < 25088) {
    int e = idx / 3136;
    int r = idx - e * 3136;
    int c = r / 49;
    int tap = r - c * 49;
    dwT[(e * 49 + tap) * 64 + c] = dw[idx];
  } else if (idx < 25088 + 65536) {
    int i = idx - 25088;
    wIn[i] = f2bf(pwin[i]);
  } else if (idx < 25088 + 65536 + 32768) {
    int i = idx - 90624;
    wOut[i] = f2bf(pwout[i]);
  }
}

// ---------------- fallback patch sums (only when ws too small for repack)
__global__ __launch_bounds__(256) void k_sum(const float* __restrict__ x,
                                             float* __restrict__ partial_l) {
  __shared__ float red[256 * 17];
  int t = threadIdx.x, bid = blockIdx.x;
  int b = bid >> 8, c = (bid >> 2) & 63, lp = bid & 3;
  const float4* x4 = (const float4*)x + ((size_t)((b * 64 + c) * 8) + lp * 2) * 4096;
#pragma unroll 1
  for (int l2 = 0; l2 < 2; ++l2) {
    float acc[16];
#pragma unroll
    for (int k = 0; k < 16; ++k) acc[k] = 0.f;
#pragma unroll
    for (int k = 0; k < 16; ++k) {
      float4 v = x4[l2 * 4096 + k * 256 + t];
      acc[k] += v.x + v.y + v.z + v.w;
    }
    int pcol = (t & 31) >> 1;
    int slot = ((t & 1) << 3) | (t >> 5);
    __syncthreads();
#pragma unroll
    for (int k = 0; k < 16; ++k) red[(k * 16 + pcol) * 17 + slot] = acc[k];
    __syncthreads();
    float s = 0.f;
#pragma unroll
    for (int j = 0; j < 16; ++j) s += red[t * 17 + j];
    partial_l[((size_t)(b * 256 + t)) * 512 + (lp * 2 + l2) * 64 + c] = s;
  }
}

// ---------------- repack x -> patch-major xr[(n*8+l)][c][px], fused patch sums
__global__ __launch_bounds__(256) void k_repack(const float* __restrict__ x,
                                                float* __restrict__ xr,
                                                float* __restrict__ partial_l) {
  __shared__ __align__(16) float lt[8 * 1060];
  int t = threadIdx.x, bid = blockIdx.x;
  int ct = bid & 7, hh = (bid >> 3) & 15, l = (bid >> 7) & 7, b = bid >> 10;
  int c0 = ct * 8;
  const float4* x4 = (const float4*)x;
  float4* xr4 = (float4*)xr;
  int y = t >> 5, xq = t & 31;
#pragma unroll
  for (int i = 0; i < 8; ++i) {
    size_t src = ((size_t)((b * 64 + c0 + i) * 8 + l) << 12) +
                 (size_t)(hh * 8 + y) * 32 + xq;
    float4 v = x4[src];
    *(float4*)(lt + i * 1060 + y * 132 + xq * 4) = v;
  }
  __syncthreads();
  int cc = (t >> 4) & 7, ihalf = t >> 7, pxq = t & 15;
  int py = pxq >> 1, xcol = pxq & 1;
#pragma unroll
  for (int iw = 0; iw < 8; ++iw) {
    int ww = ihalf * 8 + iw;
    float4 v = *(const float4*)(lt + cc * 1060 + py * 132 + ww * 8 + xcol * 4);
    int n = b * 256 + hh * 16 + ww;
    xr4[((size_t)(n * 8 + l) << 10) + (c0 + cc) * 16 + pxq] = v;
    float s = v.x + v.y + v.z + v.w;
#pragma unroll
    for (int m = 1; m < 16; m <<= 1) s += __shfl_xor(s, m, 64);
    if (pxq == 0) partial_l[(size_t)(n * 8 + l) * 64 + c0 + cc] = s;
  }
}

// ---------------- router
__global__ void k_router(const float* __restrict__ partial_l,
                         const float* __restrict__ rw, const float* __restrict__ rb,
                         int* __restrict__ sel_i, float* __restrict__ sel_w) {
  int n = blockIdx.x;
  int lane = threadIdx.x;
  float s = 0.f;
#pragma unroll
  for (int l = 0; l < 8; ++l)
    s += partial_l[(size_t)n * 512 + l * 64 + lane];
  float rin = s * (1.f / 512.f);
  float lg[8];
#pragma unroll
  for (int e = 0; e < 8; ++e) {
    float v = rin * rw[e * 64 + lane];
    lg[e] = wave_sum64(v) + rb[e];
  }
  int e0 = 0; float v0 = lg[0];
#pragma unroll
  for (int e = 1; e < 8; ++e) if (lg[e] > v0) { v0 = lg[e]; e0 = e; }
  int e1 = -1; float v1 = -1e30f;
#pragma unroll
  for (int e = 0; e < 8; ++e) if (e != e0 && lg[e] > v1) { v1 = lg[e]; e1 = e; }
  if (lane == 0) {
    float w1 = __expf(v1 - v0);
    float z = 1.f + w1;
    sel_i[2 * n] = e0; sel_i[2 * n + 1] = e1;
    sel_w[2 * n] = 1.f / z; sel_w[2 * n + 1] = w1 / z;
  }
}

// ---------------- main: one block per (patch n, depth l); 8 waves of 64
template <bool REPACK>
__global__ __launch_bounds__(512) void k_main(
    const float* __restrict__ x, const float* __restrict__ xr,
    const float* __restrict__ dwT, const float* __restrict__ dwb,
    const float* __restrict__ lnw, const float* __restrict__ lnb,
    const float* __restrict__ pwin_b, const float* __restrict__ pwout_b,
    const unsigned short* __restrict__ wInBf,
    const unsigned short* __restrict__ wOutBf,
    const int* __restrict__ sel_i, const float* __restrict__ sel_w,
    float* __restrict__ out) {
  // carve: wsdw f32[3136] @0 | hbf u16[64*72] @12544 | h3bf u16[64*72] @21760
  //        | lnred f32[16*64] @30976 | xs f32[64*66] @35072  => 51968 B (3/CU)
  __shared__ __align__(16) char smem[51968];
  float* wsdw          = (float*)smem;
  unsigned short* hbf  = (unsigned short*)(smem + 12544);
  unsigned short* h3bf = (unsigned short*)(smem + 21760);
  float* lnred         = (float*)(smem + 30976);
  float* xs            = (float*)(smem + 35072);
  float* eb            = (float*)smem;  // epilogue alias over wsdw+hbf[0:4864)

  const int t = threadIdx.x;
  const int lane = t & 63;
  const int wv = __builtin_amdgcn_readfirstlane(t >> 6);  // 0..7
  const int wi = wv >> 1;      // MFMA row-tile index 0..3
  const int jh = wv & 1;       // px-half 0..1
  const int r15 = lane & 15, r4 = lane >> 4;
  const int bidx = blockIdx.x;
  const int n = bidx >> 3, l = bidx & 7;
  const int b = n >> 8, p = n & 255;
  const int hh = p >> 4, ww = p & 15;
  const size_t obase = (size_t)b * 8388608 + (size_t)l * 16384 +
                       (size_t)hh * 1024 + (size_t)ww * 8;

  // ---- stage x slice -> xs [c][px] stride 66 (float2 granularity)
#pragma unroll
  for (int it = 0; it < 2; ++it) {
    int g = it * 512 + t;
    int c = g >> 4, q = g & 15;
    float4 v;
    if constexpr (REPACK)
      v = ((const float4*)xr)[(size_t)bidx * 1024 + g];
    else
      v = *(const float4*)(x + obase + (size_t)c * 131072 + (q >> 1) * 128 + (q & 1) * 4);
    *(float2*)(xs + c * 66 + q * 4)     = float2{v.x, v.y};
    *(float2*)(xs + c * 66 + q * 4 + 2) = float2{v.z, v.w};
  }

  float oacc[8];
#pragma unroll
  for (int i = 0; i < 8; ++i) oacc[i] = 0.f;

#pragma unroll 1
  for (int k = 0; k < 2; ++k) {
    const int e = __builtin_amdgcn_readfirstlane(sel_i[2 * n + k]);
    const float we = sel_w[2 * n + k];

    // ---- stage expert dw weights into LDS (784 float4, 512 threads)
    {
      const float4* src = (const float4*)(dwT + e * 3136);
      float4* dst = (float4*)wsdw;
      dst[t] = src[t];
      if (t < 272) dst[512 + t] = src[512 + t];
    }
    __syncthreads();  // syncW: wsdw + xs ready (k=0); guards hbf/h3bf reuse (k=1)

    // ---- depthwise conv: lane = channel; wave wv owns output row wv (8 px)
    float hv[8];
    {
      const float bias = dwb[e * 64 + lane];
#pragma unroll
      for (int j = 0; j < 8; ++j) hv[j] = bias;
    }
    {
      const float* rowp = xs + lane * 66;
      const float* wl = wsdw + lane;
      const int y0 = wv;
      const int rlo = (y0 - 3 < 0) ? 0 : y0 - 3;
      const int rhi = (y0 + 3 > 7) ? 7 : y0 + 3;
      for (int r = rlo; r <= rhi; ++r) {   // runtime loop: small code, few regs
        const float* xrow = rowp + r * 8;
        float2 p0 = *(const float2*)(xrow);
        float2 p1 = *(const float2*)(xrow + 2);
        float2 p2 = *(const float2*)(xrow + 4);
        float2 p3 = *(const float2*)(xrow + 6);
        const float row[8] = {p0.x, p0.y, p1.x, p1.y, p2.x, p2.y, p3.x, p3.y};
        const float* wrow = wl + (r - y0 + 3) * 7 * 64;
#pragma unroll
        for (int dx = 0; dx < 7; ++dx) {
          float wt = wrow[dx * 64];   // ds_read_b32, 2-way (free)
#pragma unroll
          for (int xp = 0; xp < 8; ++xp) {
            const int xx = xp + dx - 3;
            if (xx >= 0 && xx < 8) hv[xp] += row[xx] * wt;
          }
        }
      }
    }

    // ---- LayerNorm over 64 pixels per channel (8 wave-partials)
    float ps = 0.f, pq = 0.f;
#pragma unroll
    for (int j = 0; j < 8; ++j) { ps += hv[j]; pq += hv[j] * hv[j]; }
    lnred[(wv * 2 + 0) * 64 + lane] = ps;
    lnred[(wv * 2 + 1) * 64 + lane] = pq;
    __syncthreads();  // sync1
    float sm = 0.f, sq = 0.f;
#pragma unroll
    for (int w = 0; w < 8; ++w) {
      sm += lnred[(2 * w + 0) * 64 + lane];
      sq += lnred[(2 * w + 1) * 64 + lane];
    }
    float mu = sm * (1.f / 64.f);
    float var = sq * (1.f / 64.f) - mu * mu;
    float rstd = rsqrtf(var + 1e-5f);
#pragma unroll
    for (int j = 0; j < 8; ++j) {
      int s = wv * 8 + j;  // pixel index owned by this wave
      float nv = (hv[j] - mu) * rstd * lnw[e * 64 + s] + lnb[e * 64 + s];
      hbf[s * 72 + lane] = f2bf(nv);  // h[px][c] bf16, stride 72
    }
    __syncthreads();  // sync2: h ready

    // ---- pw_in (64->128) MFMA; wave owns A-rows [16wi,+16), G-rows +64,
    //      px-tiles {2jh, 2jh+1}
    const unsigned short* wInE = wInBf + (size_t)e * 8192;
    short8 aA[2], aG[2];
#pragma unroll
    for (int kf = 0; kf < 2; ++kf) {
      aA[kf] = *(const short8*)(wInE + (16 * wi + r15) * 64 + kf * 32 + r4 * 8);
      aG[kf] = *(const short8*)(wInE + (64 + 16 * wi + r15) * 64 + kf * 32 + r4 * 8);
    }
    f32x4 accA[2], accG[2];
#pragma unroll
    for (int ntl = 0; ntl < 2; ++ntl)
#pragma unroll
      for (int v = 0; v < 4; ++v) {
        accA[ntl][v] = pwin_b[e * 128 + 16 * wi + r4 * 4 + v];
        accG[ntl][v] = pwin_b[e * 128 + 64 + 16 * wi + r4 * 4 + v];
      }
#pragma unroll
    for (int ntl = 0; ntl < 2; ++ntl) {
      const int nt = 2 * jh + ntl;
#pragma unroll
      for (int kf = 0; kf < 2; ++kf) {
        short8 bfr = *(const short8*)(hbf + (16 * nt + r15) * 72 + kf * 32 + r4 * 8);
        accA[ntl] = __builtin_amdgcn_mfma_f32_16x16x32_bf16(aA[kf], bfr, accA[ntl], 0, 0, 0);
        accG[ntl] = __builtin_amdgcn_mfma_f32_16x16x32_bf16(aG[kf], bfr, accG[ntl], 0, 0, 0);
      }
    }
    // silu(a)*g -> h3 (separate buffer, packed uint2 = 4 bf16 channels)
#pragma unroll
    for (int ntl = 0; ntl < 2; ++ntl) {
      const int nt = 2 * jh + ntl;
      float hval[4];
#pragma unroll
      for (int v = 0; v < 4; ++v) {
        float a = accA[ntl][v];
        float g = accG[ntl][v];
        hval[v] = (a / (1.f + __expf(-a))) * g;
      }
      uint2 w2;
      w2.x = (unsigned)f2bf(hval[0]) | ((unsigned)f2bf(hval[1]) << 16);
      w2.y = (unsigned)f2bf(hval[2]) | ((unsigned)f2bf(hval[3]) << 16);
      *(uint2*)(h3bf + (16 * nt + r15) * 72 + 16 * wi + 4 * r4) = w2;
    }
    __syncthreads();  // sync3: h3 ready

    // ---- pw_out (64->64) MFMA; wave owns rows [16wi,+16), px-tiles {2jh,+1}
    const unsigned short* wOutE = wOutBf + (size_t)e * 4096;
    short8 aO[2];
#pragma unroll
    for (int kf = 0; kf < 2; ++kf)
      aO[kf] = *(const short8*)(wOutE + (16 * wi + r15) * 64 + kf * 32 + r4 * 8);
    f32x4 accO[2];
#pragma unroll
    for (int ntl = 0; ntl < 2; ++ntl)
#pragma unroll
      for (int v = 0; v < 4; ++v) accO[ntl][v] = 0.f;
#pragma unroll
    for (int ntl = 0; ntl < 2; ++ntl) {
      const int nt = 2 * jh + ntl;
#pragma unroll
      for (int kf = 0; kf < 2; ++kf) {
        short8 bfr = *(const short8*)(h3bf + (16 * nt + r15) * 72 + kf * 32 + r4 * 8);
        accO[ntl] = __builtin_amdgcn_mfma_f32_16x16x32_bf16(aO[kf], bfr, accO[ntl], 0, 0, 0);
      }
    }
    float bO[4];
#pragma unroll
    for (int v = 0; v < 4; ++v) bO[v] = pwout_b[e * 64 + 16 * wi + r4 * 4 + v];
#pragma unroll
    for (int ntl = 0; ntl < 2; ++ntl)
#pragma unroll
      for (int v = 0; v < 4; ++v) oacc[ntl * 4 + v] += we * (accO[ntl][v] + bO[v]);
  }

  // ---- epilogue: oacc -> eb (f32 [c][px] stride 68, aliases wsdw+hbf head;
  //      all reads of those regions completed before the k=1 sync3 barrier)
#pragma unroll
  for (int ntl = 0; ntl < 2; ++ntl)
#pragma unroll
    for (int v = 0; v < 4; ++v)
      eb[(16 * wi + 4 * r4 + v) * 68 + 16 * (2 * jh + ntl) + r15] = oacc[ntl * 4 + v];
  __syncthreads();
#pragma unroll
  for (int it = 0; it < 2; ++it) {
    int g = it * 512 + t;
    int c = g >> 4, q = g & 15;
    float4 dv = *(const float4*)(eb + c * 68 + q * 4);
    float2 x01 = *(const float2*)(xs + c * 66 + q * 4);
    float2 x23 = *(const float2*)(xs + c * 66 + q * 4 + 2);
    float4 o4 = {x01.x + dv.x, x01.y + dv.y, x23.x + dv.z, x23.y + dv.w};
    *(float4*)(out + obase + (size_t)c * 131072 + (q >> 1) * 128 + (q & 1) * 4) = o4;
  }
}

extern "C" void kernel_launch(void* const* d_in, const int* in_sizes, int n_in,
                              void* d_out, int out_size, void* d_ws, size_t ws_size,
                              hipStream_t stream) {
  const float* x       = (const float*)d_in[0];
  const float* rw      = (const float*)d_in[1];
  const float* rb      = (const float*)d_in[2];
  const float* dww     = (const float*)d_in[3];
  const float* dwb     = (const float*)d_in[4];
  const float* lnw     = (const float*)d_in[5];
  const float* lnb     = (const float*)d_in[6];
  const float* pwin_w  = (const float*)d_in[7];
  const float* pwin_b  = (const float*)d_in[8];
  const float* pwout_w = (const float*)d_in[9];
  const float* pwout_b = (const float*)d_in[10];
  float* out = (float*)d_out;

  char* ws = (char*)d_ws;
  float*          partial_l = (float*)ws;
  float*          dwT       = (float*)(ws + 1048576);
  int*            sel_i     = (int*)(ws + 1148928);
  float*          sel_w     = (float*)(ws + 1153024);
  unsigned short* wInBf     = (unsigned short*)(ws + 1157120);
  unsigned short* wOutBf    = (unsigned short*)(ws + 1288192);
  float*          xr        = (float*)(ws + 1353728);

  const bool repack = ws_size >= REPACK_NEED;

  hipLaunchKernelGGL(k_pre, dim3(482), dim3(256), 0, stream,
                     dww, pwin_w, pwout_w, dwT, wInBf, wOutBf);
  if (repack)
    hipLaunchKernelGGL(k_repack, dim3(2048), dim3(256), 0, stream, x, xr, partial_l);
  else
    hipLaunchKernelGGL(k_sum, dim3(512), dim3(256), 0, stream, x, partial_l);
  hipLaunchKernelGGL(k_router, dim3(512), dim3(64), 0, stream,
                     partial_l, rw, rb, sel_i, sel_w);
  if (repack)
    hipLaunchKernelGGL((k_main<true>), dim3(4096), dim3(512), 0, stream,
                       x, xr, dwT, dwb, lnw, lnb, pwin_b, pwout_b,
                       wInBf, wOutBf, sel_i, sel_w, out);
  else
    hipLaunchKernelGGL((k_main<false>), dim3(4096), dim3(512), 0, stream,
                       x, xr, dwT, dwb, lnw, lnb, pwin_b, pwout_b,
                       wInBf, wOutBf, sel_i, sel_w, out);
}

// Round 8
// 141.680 us; speedup vs baseline: 1.9975x; 1.0347x over previous
//
#include <hip/hip_runtime.h>
#include <hip/hip_bf16.h>
#include <cstddef>
#include <cstdint>

// SpatialPatchMoE on MI355X (gfx950).
// x[2,64,8,128,128] f32 -> 512 patches x 8 l-slices; router top-2/8;
// per expert: dwconv(1,7,7) -> LN(8,8) -> pw 64->128 -> silu*gate -> pw 64->64;
// out = x + sum_k w_k * expert_k.  Pointwise matmuls = bf16 MFMA 16x16x32.
//
// k_main: 512 threads = 8 waves; wave wv owns conv row wv and MFMA row-tile
// (wv>>1) x px-half (wv&1).  NO __launch_bounds__ min-waves (rounds 4-6: any
// min-waves cap makes the allocator spill 300-500 MB of scratch).
// xs uses stride 68 + XOR row swizzle r^((c>>3)&7) -> conflict-free b128 rows.
// Conv uses v_pk_fma_f32 via __builtin_elementwise_fma on padded f32x2 pairs.
//
// ws layout (bytes):
//   partial_l : f32 [n][l][c]      @ 0         (1048576)
//   dwT       : f32 [e][tap][c]    @ 1048576   (100352)
//   sel_i     : int[2*512]         @ 1148928   (4096)
//   sel_w     : f32[2*512]         @ 1153024   (4096)
//   wInBf     : bf16 [e][128][64]  @ 1157120   (131072)
//   wOutBf    : bf16 [e][64][64]   @ 1288192   (65536)
//   xr        : f32 [n*8+l][c][px] @ 1353728   (67108864)   (repack path)

typedef __attribute__((ext_vector_type(8))) short short8;
typedef __attribute__((ext_vector_type(4))) float f32x4;
typedef __attribute__((ext_vector_type(2))) float f32x2;

#define REPACK_NEED 68462592ull

__device__ __forceinline__ unsigned short f2bf(float f) {
  return __builtin_bit_cast(unsigned short, __float2bfloat16(f));
}

__device__ __forceinline__ float wave_sum64(float v) {
#pragma unroll
  for (int m = 32; m > 0; m >>= 1) v += __shfl_xor(v, m, 64);
  return v;
}

// ---------------- preprocess: dw transpose + pw weights -> bf16
__global__ void k_pre(const float* __restrict__ dw,
                      const float* __restrict__ pwin,
                      const float* __restrict__ pwout,
                      float* __restrict__ dwT,
                      unsigned short* __restrict__ wIn,
                      unsigned short* __restrict__ wOut) {
  int idx = blockIdx.x * 256 + threadIdx.x;
  if (idx < 25088) {
    int e = idx / 3136;
    int r = idx - e * 3136;
    int c = r / 49;
    int tap = r - c * 49;
    dwT[(e * 49 + tap) * 64 + c] = dw[idx];
  } else if (idx < 25088 + 65536) {
    int i = idx - 25088;
    wIn[i] = f2bf(pwin[i]);
  } else if (idx < 25088 + 65536 + 32768) {
    int i = idx - 90624;
    wOut[i] = f2bf(pwout[i]);
  }
}

// ---------------- fallback patch sums (only when ws too small for repack)
__global__ __launch_bounds__(256) void k_sum(const float* __restrict__ x,
                                             float* __restrict__ partial_l) {
  __shared__ float red[256 * 17];
  int t = threadIdx.x, bid = blockIdx.x;
  int b = bid >> 8, c = (bid >> 2) & 63, lp = bid & 3;
  const float4* x4 = (const float4*)x + ((size_t)((b * 64 + c) * 8) + lp * 2) * 4096;
#pragma unroll 1
  for (int l2 = 0; l2 < 2; ++l2) {
    float acc[16];
#pragma unroll
    for (int k = 0; k < 16; ++k) acc[k] = 0.f;
#pragma unroll
    for (int k = 0; k < 16; ++k) {
      float4 v = x4[l2 * 4096 + k * 256 + t];
      acc[k] += v.x + v.y + v.z + v.w;
    }
    int pcol = (t & 31) >> 1;
    int slot = ((t & 1) << 3) | (t >> 5);
    __syncthreads();
#pragma unroll
    for (int k = 0; k < 16; ++k) red[(k * 16 + pcol) * 17 + slot] = acc[k];
    __syncthreads();
    float s = 0.f;
#pragma unroll
    for (int j = 0; j < 16; ++j) s += red[t * 17 + j];
    partial_l[((size_t)(b * 256 + t)) * 512 + (lp * 2 + l2) * 64 + c] = s;
  }
}

// ---------------- repack x -> patch-major xr[(n*8+l)][c][px], fused patch sums
__global__ __launch_bounds__(256) void k_repack(const float* __restrict__ x,
                                                float* __restrict__ xr,
                                                float* __restrict__ partial_l) {
  __shared__ __align__(16) float lt[8 * 1060];
  int t = threadIdx.x, bid = blockIdx.x;
  int ct = bid & 7, hh = (bid >> 3) & 15, l = (bid >> 7) & 7, b = bid >> 10;
  int c0 = ct * 8;
  const float4* x4 = (const float4*)x;
  float4* xr4 = (float4*)xr;
  int y = t >> 5, xq = t & 31;
#pragma unroll
  for (int i = 0; i < 8; ++i) {
    size_t src = ((size_t)((b * 64 + c0 + i) * 8 + l) << 12) +
                 (size_t)(hh * 8 + y) * 32 + xq;
    float4 v = x4[src];
    *(float4*)(lt + i * 1060 + y * 132 + xq * 4) = v;
  }
  __syncthreads();
  int cc = (t >> 4) & 7, ihalf = t >> 7, pxq = t & 15;
  int py = pxq >> 1, xcol = pxq & 1;
#pragma unroll
  for (int iw = 0; iw < 8; ++iw) {
    int ww = ihalf * 8 + iw;
    float4 v = *(const float4*)(lt + cc * 1060 + py * 132 + ww * 8 + xcol * 4);
    int n = b * 256 + hh * 16 + ww;
    xr4[((size_t)(n * 8 + l) << 10) + (c0 + cc) * 16 + pxq] = v;
    float s = v.x + v.y + v.z + v.w;
#pragma unroll
    for (int m = 1; m < 16; m <<= 1) s += __shfl_xor(s, m, 64);
    if (pxq == 0) partial_l[(size_t)(n * 8 + l) * 64 + c0 + cc] = s;
  }
}

// ---------------- router
__global__ void k_router(const float* __restrict__ partial_l,
                         const float* __restrict__ rw, const float* __restrict__ rb,
                         int* __restrict__ sel_i, float* __restrict__ sel_w) {
  int n = blockIdx.x;
  int lane = threadIdx.x;
  float s = 0.f;
#pragma unroll
  for (int l = 0; l < 8; ++l)
    s += partial_l[(size_t)n * 512 + l * 64 + lane];
  float rin = s * (1.f / 512.f);
  float lg[8];
#pragma unroll
  for (int e = 0; e < 8; ++e) {
    float v = rin * rw[e * 64 + lane];
    lg[e] = wave_sum64(v) + rb[e];
  }
  int e0 = 0; float v0 = lg[0];
#pragma unroll
  for (int e = 1; e < 8; ++e) if (lg[e] > v0) { v0 = lg[e]; e0 = e; }
  int e1 = -1; float v1 = -1e30f;
#pragma unroll
  for (int e = 0; e < 8; ++e) if (e != e0 && lg[e] > v1) { v1 = lg[e]; e1 = e; }
  if (lane == 0) {
    float w1 = __expf(v1 - v0);
    float z = 1.f + w1;
    sel_i[2 * n] = e0; sel_i[2 * n + 1] = e1;
    sel_w[2 * n] = 1.f / z; sel_w[2 * n + 1] = w1 / z;
  }
}

// ---------------- main: one block per (patch n, depth l); 8 waves of 64
template <bool REPACK>
__global__ __launch_bounds__(512) void k_main(
    const float* __restrict__ x, const float* __restrict__ xr,
    const float* __restrict__ dwT, const float* __restrict__ dwb,
    const float* __restrict__ lnw, const float* __restrict__ lnb,
    const float* __restrict__ pwin_b, const float* __restrict__ pwout_b,
    const unsigned short* __restrict__ wInBf,
    const unsigned short* __restrict__ wOutBf,
    const int* __restrict__ sel_i, const float* __restrict__ sel_w,
    float* __restrict__ out) {
  // carve: wsdw f32[3136] @0 | hbf u16[64*72] @12544 | h3bf u16[64*72] @21760
  //        | lnred f32[16*64] @30976 | xs f32[64*68] @35072  => 52480 B (3/CU)
  __shared__ __align__(16) char smem[52480];
  float* wsdw          = (float*)smem;
  unsigned short* hbf  = (unsigned short*)(smem + 12544);
  unsigned short* h3bf = (unsigned short*)(smem + 21760);
  float* lnred         = (float*)(smem + 30976);
  float* xs            = (float*)(smem + 35072);
  float* eb            = (float*)smem;  // epilogue alias over wsdw+hbf[0:4864)

  const int t = threadIdx.x;
  const int lane = t & 63;
  const int wv = __builtin_amdgcn_readfirstlane(t >> 6);  // 0..7
  const int wi = wv >> 1;      // MFMA row-tile index 0..3
  const int jh = wv & 1;       // px-half 0..1
  const int r15 = lane & 15, r4 = lane >> 4;
  const int bidx = blockIdx.x;
  const int n = bidx >> 3, l = bidx & 7;
  const int b = n >> 8, p = n & 255;
  const int hh = p >> 4, ww = p & 15;
  const size_t obase = (size_t)b * 8388608 + (size_t)l * 16384 +
                       (size_t)hh * 1024 + (size_t)ww * 8;

  // ---- stage x slice -> xs [c][px], stride 68, XOR row swizzle r^((c>>3)&7)
#pragma unroll
  for (int it = 0; it < 2; ++it) {
    int g = it * 512 + t;
    int c = g >> 4, q = g & 15;
    float4 v;
    if constexpr (REPACK)
      v = ((const float4*)xr)[(size_t)bidx * 1024 + g];
    else
      v = *(const float4*)(x + obase + (size_t)c * 131072 + (q >> 1) * 128 + (q & 1) * 4);
    int rs = (q >> 1) ^ ((c >> 3) & 7);
    *(float4*)(xs + c * 68 + rs * 8 + (q & 1) * 4) = v;
  }

  float oacc[8];
#pragma unroll
  for (int i = 0; i < 8; ++i) oacc[i] = 0.f;

#pragma unroll 1
  for (int k = 0; k < 2; ++k) {
    const int e = __builtin_amdgcn_readfirstlane(sel_i[2 * n + k]);
    const float we = sel_w[2 * n + k];

    // ---- stage expert dw weights into LDS (784 float4, 512 threads)
    {
      const float4* src = (const float4*)(dwT + e * 3136);
      float4* dst = (float4*)wsdw;
      dst[t] = src[t];
      if (t < 272) dst[512 + t] = src[512 + t];
    }
    __syncthreads();  // syncW: wsdw + xs ready (k=0); guards hbf/h3bf reuse (k=1)

    // ---- depthwise conv: lane = channel; wave wv owns output row wv (8 px)
    //      packed f32x2 MACs over zero-padded pairs -> v_pk_fma_f32
    f32x2 hv2[4];
    {
      const float bias = dwb[e * 64 + lane];
#pragma unroll
      for (int j = 0; j < 4; ++j) hv2[j] = f32x2{bias, bias};
    }
    {
      const float* rowbase = xs + lane * 68;
      const int rc = (lane >> 3) & 7;
      const float* wl = wsdw + lane;
      const int y0 = wv;
      const int rlo = (y0 - 3 < 0) ? 0 : y0 - 3;
      const int rhi = (y0 + 3 > 7) ? 7 : y0 + 3;
      for (int r = rlo; r <= rhi; ++r) {   // runtime loop: small code, few regs
        const float* xrow = rowbase + 8 * (r ^ rc);
        float4 a0 = *(const float4*)xrow;
        float4 a1 = *(const float4*)(xrow + 4);
        float xp[14];
        xp[0] = 0.f; xp[1] = 0.f; xp[2] = 0.f;
        xp[3] = a0.x; xp[4] = a0.y; xp[5] = a0.z; xp[6] = a0.w;
        xp[7] = a1.x; xp[8] = a1.y; xp[9] = a1.z; xp[10] = a1.w;
        xp[11] = 0.f; xp[12] = 0.f; xp[13] = 0.f;
        f32x2 pr[13];
#pragma unroll
        for (int m = 0; m < 13; ++m) pr[m] = f32x2{xp[m], xp[m + 1]};
        const float* wrow = wl + (r - y0 + 3) * 448;
#pragma unroll
        for (int dx = 0; dx < 7; ++dx) {
          float wt = wrow[dx * 64];   // ds_read_b32, 2-way (free)
          f32x2 w2 = f32x2{wt, wt};
          hv2[0] = __builtin_elementwise_fma(pr[dx + 0], w2, hv2[0]);
          hv2[1] = __builtin_elementwise_fma(pr[dx + 2], w2, hv2[1]);
          hv2[2] = __builtin_elementwise_fma(pr[dx + 4], w2, hv2[2]);
          hv2[3] = __builtin_elementwise_fma(pr[dx + 6], w2, hv2[3]);
        }
      }
    }

    // ---- LayerNorm over 64 pixels per channel (8 wave-partials)
    f32x2 ps2 = f32x2{0.f, 0.f}, pq2 = f32x2{0.f, 0.f};
#pragma unroll
    for (int j = 0; j < 4; ++j) {
      ps2 += hv2[j];
      pq2 = __builtin_elementwise_fma(hv2[j], hv2[j], pq2);
    }
    lnred[(wv * 2 + 0) * 64 + lane] = ps2.x + ps2.y;
    lnred[(wv * 2 + 1) * 64 + lane] = pq2.x + pq2.y;
    __syncthreads();  // sync1
    float sm = 0.f, sq = 0.f;
#pragma unroll
    for (int w = 0; w < 8; ++w) {
      sm += lnred[(2 * w + 0) * 64 + lane];
      sq += lnred[(2 * w + 1) * 64 + lane];
    }
    float mu = sm * (1.f / 64.f);
    float var = sq * (1.f / 64.f) - mu * mu;
    float rstd = rsqrtf(var + 1e-5f);
#pragma unroll
    for (int j = 0; j < 8; ++j) {
      int s = wv * 8 + j;  // pixel index owned by this wave
      float hvj = (j & 1) ? hv2[j >> 1].y : hv2[j >> 1].x;
      float nv = (hvj - mu) * rstd * lnw[e * 64 + s] + lnb[e * 64 + s];
      hbf[s * 72 + lane] = f2bf(nv);  // h[px][c] bf16, stride 72
    }
    __syncthreads();  // sync2: h ready

    // ---- pw_in (64->128) MFMA; wave owns A-rows [16wi,+16), G-rows +64,
    //      px-tiles {2jh, 2jh+1}
    const unsigned short* wInE = wInBf + (size_t)e * 8192;
    short8 aA[2], aG[2];
#pragma unroll
    for (int kf = 0; kf < 2; ++kf) {
      aA[kf] = *(const short8*)(wInE + (16 * wi + r15) * 64 + kf * 32 + r4 * 8);
      aG[kf] = *(const short8*)(wInE + (64 + 16 * wi + r15) * 64 + kf * 32 + r4 * 8);
    }
    f32x4 accA[2], accG[2];
#pragma unroll
    for (int ntl = 0; ntl < 2; ++ntl)
#pragma unroll
      for (int v = 0; v < 4; ++v) {
        accA[ntl][v] = pwin_b[e * 128 + 16 * wi + r4 * 4 + v];
        accG[ntl][v] = pwin_b[e * 128 + 64 + 16 * wi + r4 * 4 + v];
      }
#pragma unroll
    for (int ntl = 0; ntl < 2; ++ntl) {
      const int nt = 2 * jh + ntl;
#pragma unroll
      for (int kf = 0; kf < 2; ++kf) {
        short8 bfr = *(const short8*)(hbf + (16 * nt + r15) * 72 + kf * 32 + r4 * 8);
        accA[ntl] = __builtin_amdgcn_mfma_f32_16x16x32_bf16(aA[kf], bfr, accA[ntl], 0, 0, 0);
        accG[ntl] = __builtin_amdgcn_mfma_f32_16x16x32_bf16(aG[kf], bfr, accG[ntl], 0, 0, 0);
      }
    }
    // silu(a)*g -> h3 (separate buffer, packed uint2 = 4 bf16 channels)
#pragma unroll
    for (int ntl = 0; ntl < 2; ++ntl) {
      const int nt = 2 * jh + ntl;
      float hval[4];
#pragma unroll
      for (int v = 0; v < 4; ++v) {
        float a = accA[ntl][v];
        float g = accG[ntl][v];
        hval[v] = (a / (1.f + __expf(-a))) * g;
      }
      uint2 w2;
      w2.x = (unsigned)f2bf(hval[0]) | ((unsigned)f2bf(hval[1]) << 16);
      w2.y = (unsigned)f2bf(hval[2]) | ((unsigned)f2bf(hval[3]) << 16);
      *(uint2*)(h3bf + (16 * nt + r15) * 72 + 16 * wi + 4 * r4) = w2;
    }
    __syncthreads();  // sync3: h3 ready

    // ---- pw_out (64->64) MFMA; wave owns rows [16wi,+16), px-tiles {2jh,+1}
    const unsigned short* wOutE = wOutBf + (size_t)e * 4096;
    short8 aO[2];
#pragma unroll
    for (int kf = 0; kf < 2; ++kf)
      aO[kf] = *(const short8*)(wOutE + (16 * wi + r15) * 64 + kf * 32 + r4 * 8);
    f32x4 accO[2];
#pragma unroll
    for (int ntl = 0; ntl < 2; ++ntl)
#pragma unroll
      for (int v = 0; v < 4; ++v) accO[ntl][v] = 0.f;
#pragma unroll
    for (int ntl = 0; ntl < 2; ++ntl) {
      const int nt = 2 * jh + ntl;
#pragma unroll
      for (int kf = 0; kf < 2; ++kf) {
        short8 bfr = *(const short8*)(h3bf + (16 * nt + r15) * 72 + kf * 32 + r4 * 8);
        accO[ntl] = __builtin_amdgcn_mfma_f32_16x16x32_bf16(aO[kf], bfr, accO[ntl], 0, 0, 0);
      }
    }
    float bO[4];
#pragma unroll
    for (int v = 0; v < 4; ++v) bO[v] = pwout_b[e * 64 + 16 * wi + r4 * 4 + v];
#pragma unroll
    for (int ntl = 0; ntl < 2; ++ntl)
#pragma unroll
      for (int v = 0; v < 4; ++v) oacc[ntl * 4 + v] += we * (accO[ntl][v] + bO[v]);
  }

  // ---- epilogue: oacc -> eb (f32 [c][px] stride 68, aliases wsdw+hbf head;
  //      those regions are only read before the k=1 sync3 barrier)
#pragma unroll
  for (int ntl = 0; ntl < 2; ++ntl)
#pragma unroll
    for (int v = 0; v < 4; ++v)
      eb[(16 * wi + 4 * r4 + v) * 68 + 16 * (2 * jh + ntl) + r15] = oacc[ntl * 4 + v];
  __syncthreads();
#pragma unroll
  for (int it = 0; it < 2; ++it) {
    int g = it * 512 + t;
    int c = g >> 4, q = g & 15;
    float4 dv = *(const float4*)(eb + c * 68 + q * 4);
    int rs = (q >> 1) ^ ((c >> 3) & 7);
    float4 xv = *(const float4*)(xs + c * 68 + rs * 8 + (q & 1) * 4);
    float4 o4 = {xv.x + dv.x, xv.y + dv.y, xv.z + dv.z, xv.w + dv.w};
    *(float4*)(out + obase + (size_t)c * 131072 + (q >> 1) * 128 + (q & 1) * 4) = o4;
  }
}

extern "C" void kernel_launch(void* const* d_in, const int* in_sizes, int n_in,
                              void* d_out, int out_size, void* d_ws, size_t ws_size,
                              hipStream_t stream) {
  const float* x       = (const float*)d_in[0];
  const float* rw      = (const float*)d_in[1];
  const float* rb      = (const float*)d_in[2];
  const float* dww     = (const float*)d_in[3];
  const float* dwb     = (const float*)d_in[4];
  const float* lnw     = (const float*)d_in[5];
  const float* lnb     = (const float*)d_in[6];
  const float* pwin_w  = (const float*)d_in[7];
  const float* pwin_b  = (const float*)d_in[8];
  const float* pwout_w = (const float*)d_in[9];
  const float* pwout_b = (const float*)d_in[10];
  float* out = (float*)d_out;

  char* ws = (char*)d_ws;
  float*          partial_l = (float*)ws;
  float*          dwT       = (float*)(ws + 1048576);
  int*            sel_i     = (int*)(ws + 1148928);
  float*          sel_w     = (float*)(ws + 1153024);
  unsigned short* wInBf     = (unsigned short*)(ws + 1157120);
  unsigned short* wOutBf    = (unsigned short*)(ws + 1288192);
  float*          xr        = (float*)(ws + 1353728);

  const bool repack = ws_size >= REPACK_NEED;

  hipLaunchKernelGGL(k_pre, dim3(482), dim3(256), 0, stream,
                     dww, pwin_w, pwout_w, dwT, wInBf, wOutBf);
  if (repack)
    hipLaunchKernelGGL(k_repack, dim3(2048), dim3(256), 0, stream, x, xr, partial_l);
  else
    hipLaunchKernelGGL(k_sum, dim3(512), dim3(256), 0, stream, x, partial_l);
  hipLaunchKernelGGL(k_router, dim3(512), dim3(64), 0, stream,
                     partial_l, rw, rb, sel_i, sel_w);
  if (repack)
    hipLaunchKernelGGL((k_main<true>), dim3(4096), dim3(512), 0, stream,
                       x, xr, dwT, dwb, lnw, lnb, pwin_b, pwout_b,
                       wInBf, wOutBf, sel_i, sel_w, out);
  else
    hipLaunchKernelGGL((k_main<false>), dim3(4096), dim3(512), 0, stream,
                       x, xr, dwT, dwb, lnw, lnb, pwin_b, pwout_b,
                       wInBf, wOutBf, sel_i, sel_w, out);
}